// Round 2
// baseline (2119.885 us; speedup 1.0000x reference)
//
#include <hip/hip_runtime.h>
#include <hip/hip_bf16.h>
#include <math.h>

typedef __attribute__((ext_vector_type(8))) short short8;
typedef __attribute__((ext_vector_type(4))) float f32x4;

#define MFMA16(a,b,c) __builtin_amdgcn_mfma_f32_16x16x32_bf16((a),(b),(c),0,0,0)

__device__ __forceinline__ short f2bf(float f) {
  unsigned u = __builtin_bit_cast(unsigned, f);
  u += 0x7fffu + ((u >> 16) & 1u);
  return (short)(u >> 16);
}
__device__ __forceinline__ float bf2f(short s) {
  unsigned u = ((unsigned)(unsigned short)s) << 16;
  return __builtin_bit_cast(float, u);
}

#define SCALE_F 0.08838834764831845f

// valid rolled-window indices (VALID_ROLLED from reference, 120 entries)
__device__ const int VR_TAB[120] = {
  5,6,7,8,14,15,16,17,23,24,25,26,27,28,29,30,31,32,33,34,35,36,37,38,39,40,41,42,43,44,
  45,46,47,48,54,55,56,57,63,64,65,66,72,73,74,75,76,77,78,79,80,81,82,83,84,85,86,87,88,89,
  90,91,92,93,94,95,96,97,98,99,100,101,102,103,104,105,106,107,113,114,115,116,122,123,124,125,131,132,133,134,
  135,136,137,138,139,140,141,142,143,144,145,146,147,148,149,150,151,152,153,154,155,156,162,163,164,165,171,172,173,174
};

// ---------------- weight transpose f32[K][N] -> bf16[N][K] ----------------
__global__ __launch_bounds__(256) void wtrans_kernel(const float* __restrict__ w,
                                                     short* __restrict__ wt, int K, int N) {
  int idx = blockIdx.x * 256 + threadIdx.x;
  if (idx >= K * N) return;
  int k = idx / N, n = idx - k * N;
  wt[(size_t)n * K + k] = f2bf(w[idx]);
}

// ---------------- layernorm over C=512, f32 in -> bf16 out ----------------
__global__ __launch_bounds__(256) void ln_kernel(const float* __restrict__ x,
                                                 const float* __restrict__ g,
                                                 const float* __restrict__ be,
                                                 short* __restrict__ out) {
  typedef __attribute__((ext_vector_type(4))) float fx4;
  int row = blockIdx.x * 4 + (threadIdx.x >> 6);
  int lane = threadIdx.x & 63;
  const float* xr = x + (size_t)row * 512 + lane * 8;
  fx4 a = *(const fx4*)xr;
  fx4 c = *(const fx4*)(xr + 4);
  float s = a[0]+a[1]+a[2]+a[3]+c[0]+c[1]+c[2]+c[3];
  float ss = a[0]*a[0]+a[1]*a[1]+a[2]*a[2]+a[3]*a[3]+c[0]*c[0]+c[1]*c[1]+c[2]*c[2]+c[3]*c[3];
  for (int off = 1; off < 64; off <<= 1) {
    s  += __shfl_xor(s, off);
    ss += __shfl_xor(ss, off);
  }
  float mean = s * (1.0f/512.0f);
  float var  = ss * (1.0f/512.0f) - mean*mean;
  float rstd = rsqrtf(var + 1e-5f);
  const float* gp = g + lane*8;
  const float* bp = be + lane*8;
  short8 o;
  #pragma unroll
  for (int j = 0; j < 4; ++j) o[j]   = f2bf((a[j]-mean)*rstd*gp[j]   + bp[j]);
  #pragma unroll
  for (int j = 0; j < 4; ++j) o[4+j] = f2bf((c[j]-mean)*rstd*gp[4+j] + bp[4+j]);
  *(short8*)(out + (size_t)row * 512 + lane * 8) = o;
}

// ---------------- GEMM: C[M,N] = A[M,K](bf16) @ Bt[N,K]^T(bf16) + bias (+resid) --------
// 128x128 tile, BK=32, 4 waves (2x2 of 64x64), mfma 16x16x32 bf16.
template<int OUT_BF16, int RESID>
__global__ __launch_bounds__(256) void gemm_kernel(
    const short* __restrict__ A, const short* __restrict__ Bt,
    const float* __restrict__ bias, const float* __restrict__ resid,
    void* __restrict__ outp, int N, int K) {
  const int m0 = blockIdx.x * 128, n0 = blockIdx.y * 128;
  const int tid = threadIdx.x;
  const int wave = tid >> 6, lane = tid & 63, lg = lane >> 4, lc = lane & 15;
  const int wr = wave >> 1, wc = wave & 1;
  __shared__ short As[128][40];   // +8 pad: conflict-free ds_read_b128
  __shared__ short Bs[128][40];
  f32x4 acc[4][4];
  #pragma unroll
  for (int i = 0; i < 4; ++i)
    #pragma unroll
    for (int j = 0; j < 4; ++j) { acc[i][j][0]=0.f; acc[i][j][1]=0.f; acc[i][j][2]=0.f; acc[i][j][3]=0.f; }
  const int steps = (K + 31) >> 5;
  for (int kt = 0; kt < steps; ++kt) {
    const int k0 = kt << 5;
    __syncthreads();
    #pragma unroll
    for (int it = 0; it < 2; ++it) {
      int row = (tid >> 2) + (it << 6);
      int kk = k0 + (tid & 3) * 8;
      short8 av = {0,0,0,0,0,0,0,0};
      short8 bv = {0,0,0,0,0,0,0,0};
      if (kk + 8 <= K) {
        av = *(const short8*)(A + (size_t)(m0 + row) * K + kk);
        int nrow = n0 + row;
        if (nrow < N) bv = *(const short8*)(Bt + (size_t)nrow * K + kk);
      }
      *(short8*)&As[row][(tid & 3) * 8] = av;
      *(short8*)&Bs[row][(tid & 3) * 8] = bv;
    }
    __syncthreads();
    short8 af[4], bfv[4];
    #pragma unroll
    for (int i = 0; i < 4; ++i) af[i]  = *(const short8*)&As[wr*64 + i*16 + lc][lg*8];
    #pragma unroll
    for (int j = 0; j < 4; ++j) bfv[j] = *(const short8*)&Bs[wc*64 + j*16 + lc][lg*8];
    #pragma unroll
    for (int i = 0; i < 4; ++i)
      #pragma unroll
      for (int j = 0; j < 4; ++j)
        acc[i][j] = MFMA16(af[i], bfv[j], acc[i][j]);
  }
  // epilogue: D row = 4*lg + r, col = lc within each 16x16
  #pragma unroll
  for (int j = 0; j < 4; ++j) {
    int col = n0 + wc*64 + j*16 + lc;
    if (col >= N) continue;
    float bb = bias[col];
    #pragma unroll
    for (int i = 0; i < 4; ++i) {
      #pragma unroll
      for (int r = 0; r < 4; ++r) {
        int rowg = m0 + wr*64 + i*16 + lg*4 + r;
        float v = acc[i][j][r] + bb;
        if (RESID) v += resid[(size_t)rowg * N + col];
        if (OUT_BF16) ((short*)outp)[(size_t)rowg * N + col] = f2bf(v);
        else          ((float*)outp)[(size_t)rowg * N + col] = v;
      }
    }
  }
}

// ---------------- windowed attention (flash-style) ----------------
// grid: (qb=6, head=4, win=64). block 256 = 4 waves; wave owns 16 q-rows.
// keys: 0..359 in-window (t*45+p), 360..1319 rolled (t*120+vi via VR_TAB).
__global__ __launch_bounds__(256) void attn_kernel(const short* __restrict__ qkv,
                                                   short* __restrict__ aout) {
  const int qb = blockIdx.x, h = blockIdx.y, win = blockIdx.z;
  const int b = win >> 4, hb = (win >> 2) & 3, wb = win & 3;
  const int tid = threadIdx.x;
  const int wave = tid >> 6, lane = tid & 63, lg = lane >> 4, lc = lane & 15;

  __shared__ short Kc[64][136];   // keys row-major [key][d], padded stride
  __shared__ short Vt[128][72];   // V transposed [d][key], padded stride
  __shared__ short Pl[4][16][40]; // per-wave P bounce [q][key32], padded

  // Q A-fragments: row = lc, d = ks*32 + lg*8 + j
  int qa = qb*64 + wave*16 + lc; if (qa > 359) qa = 359;
  int tq = qa / 45, pq = qa - tq * 45;
  int mq = ((b*8 + tq)*20 + hb*5 + pq/9)*36 + wb*9 + (pq%9);
  const short* qptr = qkv + (size_t)mq * 1536 + h*128 + lg*8;
  short8 a_q[4];
  #pragma unroll
  for (int ks = 0; ks < 4; ++ks) a_q[ks] = *(const short8*)(qptr + ks*32);

  float m_run[4], l_run[4];
  f32x4 o_acc[8];
  #pragma unroll
  for (int i = 0; i < 4; ++i) { m_run[i] = -INFINITY; l_run[i] = 0.f; }
  #pragma unroll
  for (int dt = 0; dt < 8; ++dt) { o_acc[dt][0]=0.f; o_acc[dt][1]=0.f; o_acc[dt][2]=0.f; o_acc[dt][3]=0.f; }

  const int kl = tid >> 2, qpart = tid & 3;

  for (int c0 = 0; c0 < 21; ++c0) {
    // ---- stage 64 keys (K row-major, V transposed) ----
    int n = c0*64 + kl;
    bool valid = (n < 1320);
    int mk = 0;
    if (valid) {
      int t, gh, gw;
      if (n < 360) {
        t = n / 45; int p = n - t*45;
        gh = hb*5 + p/9; gw = wb*9 + (p%9);
      } else {
        int n2 = n - 360; t = n2 / 120; int vi = n2 - t*120;
        int f = VR_TAB[vi]; int s = f / 45; int p = f - s*45;
        int r = p / 9, cc = p - r*9;
        int sh0 = (s < 2) ? -2 : 2;
        int sh1 = (s & 1) ? 4 : -4;
        gh = (hb*5 + r - sh0 + 20) % 20;
        gw = (wb*9 + cc - sh1 + 36) % 36;
      }
      mk = ((b*8 + t)*20 + gh)*36 + gw;
    }
    const short* kp = qkv + (size_t)mk * 1536 + 512 + h*128 + qpart*32;
    #pragma unroll
    for (int u = 0; u < 4; ++u) {
      short8 kv = {0,0,0,0,0,0,0,0};
      short8 vv = {0,0,0,0,0,0,0,0};
      if (valid) {
        kv = *(const short8*)(kp + u*8);
        vv = *(const short8*)(kp + 512 + u*8);
      }
      int d0 = qpart*32 + u*8;
      *(short8*)&Kc[kl][d0] = kv;
      #pragma unroll
      for (int jj = 0; jj < 8; ++jj) Vt[d0 + jj][kl] = vv[jj];
    }
    __syncthreads();

    #pragma unroll
    for (int kt2 = 0; kt2 < 2; ++kt2) {
      const int kb = kt2 * 32;
      f32x4 s0, s1;
      s0[0]=0.f;s0[1]=0.f;s0[2]=0.f;s0[3]=0.f;
      s1[0]=0.f;s1[1]=0.f;s1[2]=0.f;s1[3]=0.f;
      #pragma unroll
      for (int ks = 0; ks < 4; ++ks) {
        short8 b0 = *(const short8*)&Kc[kb + lc][ks*32 + lg*8];
        short8 b1 = *(const short8*)&Kc[kb + 16 + lc][ks*32 + lg*8];
        s0 = MFMA16(a_q[ks], b0, s0);
        s1 = MFMA16(a_q[ks], b1, s1);
      }
      int key0 = c0*64 + kb + lc;
      bool v0k = key0 < 1320, v1k = (key0 + 16) < 1320;
      float p0[4], p1[4], fs[4];
      #pragma unroll
      for (int i = 0; i < 4; ++i) {
        float a0 = v0k ? s0[i] * SCALE_F : -1e30f;
        float a1 = v1k ? s1[i] * SCALE_F : -1e30f;
        float tm = fmaxf(a0, a1);
        for (int off = 1; off < 16; off <<= 1) tm = fmaxf(tm, __shfl_xor(tm, off));
        float mn = fmaxf(m_run[i], tm);
        float f = __expf(m_run[i] - mn);
        p0[i] = __expf(a0 - mn);
        p1[i] = __expf(a1 - mn);
        float ps = p0[i] + p1[i];
        for (int off = 1; off < 16; off <<= 1) ps += __shfl_xor(ps, off);
        l_run[i] = l_run[i] * f + ps;
        m_run[i] = mn;
        fs[i] = f;
      }
      #pragma unroll
      for (int dt = 0; dt < 8; ++dt)
        #pragma unroll
        for (int i = 0; i < 4; ++i) o_acc[dt][i] *= fs[i];
      // P bounce: D row 4*lg+i -> A-frag row lc
      #pragma unroll
      for (int i = 0; i < 4; ++i) {
        Pl[wave][4*lg + i][lc]      = f2bf(p0[i]);
        Pl[wave][4*lg + i][16 + lc] = f2bf(p1[i]);
      }
      __syncthreads();
      short8 pa = *(const short8*)&Pl[wave][lc][lg*8];
      #pragma unroll
      for (int dt = 0; dt < 8; ++dt) {
        short8 bv = *(const short8*)&Vt[dt*16 + lc][kb + lg*8];
        o_acc[dt] = MFMA16(pa, bv, o_acc[dt]);
      }
      __syncthreads();
    }
  }
  // epilogue: O row 4*lg+i, col dt*16+lc
  #pragma unroll
  for (int i = 0; i < 4; ++i) {
    int q = qb*64 + wave*16 + 4*lg + i;
    if (q >= 360) continue;
    float inv = 1.0f / l_run[i];
    int t = q / 45, p = q - t*45;
    int m = ((b*8 + t)*20 + hb*5 + p/9)*36 + wb*9 + (p%9);
    short* op = aout + (size_t)m * 512 + h*128 + lc;
    #pragma unroll
    for (int dt = 0; dt < 8; ++dt) op[dt*16] = f2bf(o_acc[dt][i] * inv);
  }
}

// ---------------- fold/unfold smoothing: h1(bf16 [23040][1960]) -> smooth f32 [32][40][60][108]
__global__ __launch_bounds__(256) void smooth_kernel(const short* __restrict__ h1,
                                                     float* __restrict__ sm) {
  int t = blockIdx.x * 256 + threadIdx.x;
  if (t >= 32*40*60*108) return;
  int x = t % 108;
  int y = (t / 108) % 60;
  int c40 = (t / 6480) % 40;
  int n = t / 259200;
  float s = 0.f; int cnt = 0;
  int kh0 = y % 3, kw0 = x % 3;
  for (int kh = kh0; kh < 7; kh += 3) {
    int dy = y + 3 - kh;
    if (dy < 0) continue;
    int oy = dy / 3;
    if (oy >= 20) continue;
    for (int kw = kw0; kw < 7; kw += 3) {
      int dx = x + 3 - kw;
      if (dx < 0) continue;
      int ox = dx / 3;
      if (ox >= 36) continue;
      s += bf2f(h1[(size_t)(n*720 + oy*36 + ox) * 1960 + c40*49 + kh*7 + kw]);
      ++cnt;
    }
  }
  sm[t] = s / (float)cnt;
}

// ---------------- unfold + depthwise conv (3x3 / 5x5) + exact GELU -> h3 bf16 [23040][1960]
__global__ __launch_bounds__(256) void conv_gelu_kernel(
    const float* __restrict__ sm,
    const float* __restrict__ w3, const float* __restrict__ b3,
    const float* __restrict__ w5, const float* __restrict__ b5,
    short* __restrict__ h3) {
  int m = blockIdx.x;
  int ch = blockIdx.y * 256 + threadIdx.x;
  if (ch >= 1960) return;
  int n = m / 720, p = m - n*720;
  int gh = p / 36, gw = p - gh*36;
  int c40 = ch / 49, k = ch - c40*49;
  int kh = k / 7, kw = k - kh*7;
  const float* smc = sm + (size_t)(n*40 + c40) * 6480;
  float accv;
  if (ch < 980) {
    const float* w = w3 + ch*9;
    accv = b3[ch];
    #pragma unroll
    for (int dy = -1; dy <= 1; ++dy) {
      int iy = gh + dy; if (iy < 0 || iy >= 20) continue;
      int y = kh + 3*iy - 3; if (y < 0 || y >= 60) continue;
      #pragma unroll
      for (int dx = -1; dx <= 1; ++dx) {
        int ix = gw + dx; if (ix < 0 || ix >= 36) continue;
        int xx = kw + 3*ix - 3; if (xx < 0 || xx >= 108) continue;
        accv += w[(dy+1)*3 + dx + 1] * smc[y*108 + xx];
      }
    }
  } else {
    const float* w = w5 + (size_t)(ch - 980)*25;
    accv = b5[ch - 980];
    #pragma unroll
    for (int dy = -2; dy <= 2; ++dy) {
      int iy = gh + dy; if (iy < 0 || iy >= 20) continue;
      int y = kh + 3*iy - 3; if (y < 0 || y >= 60) continue;
      #pragma unroll
      for (int dx = -2; dx <= 2; ++dx) {
        int ix = gw + dx; if (ix < 0 || ix >= 36) continue;
        int xx = kw + 3*ix - 3; if (xx < 0 || xx >= 108) continue;
        accv += w[(dy+2)*5 + dx + 2] * smc[y*108 + xx];
      }
    }
  }
  float g = 0.5f * accv * (1.f + erff(accv * 0.70710678118654752f));
  h3[(size_t)m * 1960 + ch] = f2bf(g);
}

// ---------------- launch ----------------
extern "C" void kernel_launch(void* const* d_in, const int* in_sizes, int n_in,
                              void* d_out, int out_size, void* d_ws, size_t ws_size,
                              hipStream_t stream) {
  const float* x      = (const float*)d_in[0];
  const float* ln1_g  = (const float*)d_in[1];
  const float* ln1_b  = (const float*)d_in[2];
  const float* ln2_g  = (const float*)d_in[3];
  const float* ln2_b  = (const float*)d_in[4];
  const float* w_qkv  = (const float*)d_in[5];
  const float* b_qkv  = (const float*)d_in[6];
  const float* w_proj = (const float*)d_in[7];
  const float* b_proj = (const float*)d_in[8];
  const float* w_fc1  = (const float*)d_in[9];
  const float* b_fc1  = (const float*)d_in[10];
  const float* w_c3   = (const float*)d_in[11];
  const float* b_c3   = (const float*)d_in[12];
  const float* w_c5   = (const float*)d_in[13];
  const float* b_c5   = (const float*)d_in[14];
  const float* w_fc2  = (const float*)d_in[15];
  const float* b_fc2  = (const float*)d_in[16];

  char* ws = (char*)d_ws;
  short* wqkvT  = (short*)(ws + 0);            // 1,572,864
  short* wprojT = (short*)(ws + 1572864);      //   524,288
  short* wfc1T  = (short*)(ws + 2097152);      // 2,007,040
  short* wfc2T  = (short*)(ws + 4104192);      // 2,007,040
  short* lnb    = (short*)(ws + 6111232);      // 23,592,960  (ln1 out, later ln2 out)
  short* bigb   = (short*)(ws + 29704192);     // 90,316,800  (qkv -> h1 -> h3)
  short* attnb  = (short*)(ws + 120020992);    // 23,592,960
  float* x2     = (float*)(ws + 143613952);    // 47,185,920
  float* smooth = (float*)(ws + 190799872);    // 33,177,600  (total 223,977,472)

  // bf16 transposed weights
  wtrans_kernel<<<(512*1536 + 255)/256, 256, 0, stream>>>(w_qkv, wqkvT, 512, 1536);
  wtrans_kernel<<<(512*512  + 255)/256, 256, 0, stream>>>(w_proj, wprojT, 512, 512);
  wtrans_kernel<<<(512*1960 + 255)/256, 256, 0, stream>>>(w_fc1, wfc1T, 512, 1960);
  wtrans_kernel<<<(1960*512 + 255)/256, 256, 0, stream>>>(w_fc2, wfc2T, 1960, 512);

  // attention branch
  ln_kernel<<<5760, 256, 0, stream>>>(x, ln1_g, ln1_b, lnb);
  gemm_kernel<1,0><<<dim3(180,12), 256, 0, stream>>>(lnb, wqkvT, b_qkv, nullptr, bigb, 1536, 512);
  attn_kernel<<<dim3(6,4,64), 256, 0, stream>>>(bigb, attnb);
  gemm_kernel<0,1><<<dim3(180,4), 256, 0, stream>>>(attnb, wprojT, b_proj, x, x2, 512, 512);

  // FFN branch
  ln_kernel<<<5760, 256, 0, stream>>>(x2, ln2_g, ln2_b, lnb);
  gemm_kernel<1,0><<<dim3(180,16), 256, 0, stream>>>(lnb, wfc1T, b_fc1, nullptr, bigb, 1960, 512);
  smooth_kernel<<<(32*40*60*108 + 255)/256, 256, 0, stream>>>(bigb, smooth);
  conv_gelu_kernel<<<dim3(23040, 8), 256, 0, stream>>>(smooth, w_c3, b_c3, w_c5, b_c5, bigb);
  gemm_kernel<0,1><<<dim3(180,4), 256, 0, stream>>>(bigb, wfc2T, b_fc2, x2, (float*)d_out, 512, 1960);
}

// Round 3
// 1225.672 us; speedup vs baseline: 1.7296x; 1.7296x over previous
//
#include <hip/hip_runtime.h>
#include <hip/hip_bf16.h>
#include <math.h>

typedef __attribute__((ext_vector_type(8))) short short8;
typedef __attribute__((ext_vector_type(4))) float f32x4;

#define MFMA16(a,b,c) __builtin_amdgcn_mfma_f32_16x16x32_bf16((a),(b),(c),0,0,0)

__device__ __forceinline__ short f2bf(float f) {
  unsigned u = __builtin_bit_cast(unsigned, f);
  u += 0x7fffu + ((u >> 16) & 1u);
  return (short)(u >> 16);
}
__device__ __forceinline__ float bf2f(short s) {
  unsigned u = ((unsigned)(unsigned short)s) << 16;
  return __builtin_bit_cast(float, u);
}

#define SCALE_F 0.08838834764831845f

// valid rolled-window indices (VALID_ROLLED from reference, 120 entries)
__device__ const int VR_TAB[120] = {
  5,6,7,8,14,15,16,17,23,24,25,26,27,28,29,30,31,32,33,34,35,36,37,38,39,40,41,42,43,44,
  45,46,47,48,54,55,56,57,63,64,65,66,72,73,74,75,76,77,78,79,80,81,82,83,84,85,86,87,88,89,
  90,91,92,93,94,95,96,97,98,99,100,101,102,103,104,105,106,107,113,114,115,116,122,123,124,125,131,132,133,134,
  135,136,137,138,139,140,141,142,143,144,145,146,147,148,149,150,151,152,153,154,155,156,162,163,164,165,171,172,173,174
};

// ---------------- weight transpose f32[K][N] -> bf16[N][K] ----------------
__global__ __launch_bounds__(256) void wtrans_kernel(const float* __restrict__ w,
                                                     short* __restrict__ wt, int K, int N) {
  int idx = blockIdx.x * 256 + threadIdx.x;
  if (idx >= K * N) return;
  int k = idx / N, n = idx - k * N;
  wt[(size_t)n * K + k] = f2bf(w[idx]);
}

// ---------------- layernorm over C=512, f32 in -> bf16 out ----------------
__global__ __launch_bounds__(256) void ln_kernel(const float* __restrict__ x,
                                                 const float* __restrict__ g,
                                                 const float* __restrict__ be,
                                                 short* __restrict__ out) {
  typedef __attribute__((ext_vector_type(4))) float fx4;
  int row = blockIdx.x * 4 + (threadIdx.x >> 6);
  int lane = threadIdx.x & 63;
  const float* xr = x + (size_t)row * 512 + lane * 8;
  fx4 a = *(const fx4*)xr;
  fx4 c = *(const fx4*)(xr + 4);
  float s = a[0]+a[1]+a[2]+a[3]+c[0]+c[1]+c[2]+c[3];
  float ss = a[0]*a[0]+a[1]*a[1]+a[2]*a[2]+a[3]*a[3]+c[0]*c[0]+c[1]*c[1]+c[2]*c[2]+c[3]*c[3];
  for (int off = 1; off < 64; off <<= 1) {
    s  += __shfl_xor(s, off);
    ss += __shfl_xor(ss, off);
  }
  float mean = s * (1.0f/512.0f);
  float var  = ss * (1.0f/512.0f) - mean*mean;
  float rstd = rsqrtf(var + 1e-5f);
  const float* gp = g + lane*8;
  const float* bp = be + lane*8;
  short8 o;
  #pragma unroll
  for (int j = 0; j < 4; ++j) o[j]   = f2bf((a[j]-mean)*rstd*gp[j]   + bp[j]);
  #pragma unroll
  for (int j = 0; j < 4; ++j) o[4+j] = f2bf((c[j]-mean)*rstd*gp[4+j] + bp[4+j]);
  *(short8*)(out + (size_t)row * 512 + lane * 8) = o;
}

// ---------------- GEMM: C[M,N] = A[M,K](bf16) @ Bt[N,K]^T(bf16) + bias (+resid) --------
// 128x128 tile, BK=32, 4 waves (2x2 of 64x64), mfma 16x16x32 bf16.
template<int OUT_BF16, int RESID>
__global__ __launch_bounds__(256) void gemm_kernel(
    const short* __restrict__ A, const short* __restrict__ Bt,
    const float* __restrict__ bias, const float* __restrict__ resid,
    void* __restrict__ outp, int N, int K) {
  const int m0 = blockIdx.x * 128, n0 = blockIdx.y * 128;
  const int tid = threadIdx.x;
  const int wave = tid >> 6, lane = tid & 63, lg = lane >> 4, lc = lane & 15;
  const int wr = wave >> 1, wc = wave & 1;
  __shared__ short As[128][40];   // +8 pad: conflict-free ds_read_b128
  __shared__ short Bs[128][40];
  f32x4 acc[4][4];
  #pragma unroll
  for (int i = 0; i < 4; ++i)
    #pragma unroll
    for (int j = 0; j < 4; ++j) { acc[i][j][0]=0.f; acc[i][j][1]=0.f; acc[i][j][2]=0.f; acc[i][j][3]=0.f; }
  const int steps = (K + 31) >> 5;
  for (int kt = 0; kt < steps; ++kt) {
    const int k0 = kt << 5;
    __syncthreads();
    #pragma unroll
    for (int it = 0; it < 2; ++it) {
      int row = (tid >> 2) + (it << 6);
      int kk = k0 + (tid & 3) * 8;
      short8 av = {0,0,0,0,0,0,0,0};
      short8 bv = {0,0,0,0,0,0,0,0};
      if (kk + 8 <= K) {
        av = *(const short8*)(A + (size_t)(m0 + row) * K + kk);
        int nrow = n0 + row;
        if (nrow < N) bv = *(const short8*)(Bt + (size_t)nrow * K + kk);
      }
      *(short8*)&As[row][(tid & 3) * 8] = av;
      *(short8*)&Bs[row][(tid & 3) * 8] = bv;
    }
    __syncthreads();
    short8 af[4], bfv[4];
    #pragma unroll
    for (int i = 0; i < 4; ++i) af[i]  = *(const short8*)&As[wr*64 + i*16 + lc][lg*8];
    #pragma unroll
    for (int j = 0; j < 4; ++j) bfv[j] = *(const short8*)&Bs[wc*64 + j*16 + lc][lg*8];
    #pragma unroll
    for (int i = 0; i < 4; ++i)
      #pragma unroll
      for (int j = 0; j < 4; ++j)
        acc[i][j] = MFMA16(af[i], bfv[j], acc[i][j]);
  }
  // epilogue: D row = 4*lg + r, col = lc within each 16x16
  #pragma unroll
  for (int j = 0; j < 4; ++j) {
    int col = n0 + wc*64 + j*16 + lc;
    if (col >= N) continue;
    float bb = bias[col];
    #pragma unroll
    for (int i = 0; i < 4; ++i) {
      #pragma unroll
      for (int r = 0; r < 4; ++r) {
        int rowg = m0 + wr*64 + i*16 + lg*4 + r;
        float v = acc[i][j][r] + bb;
        if (RESID) v += resid[(size_t)rowg * N + col];
        if (OUT_BF16) ((short*)outp)[(size_t)rowg * N + col] = f2bf(v);
        else          ((float*)outp)[(size_t)rowg * N + col] = v;
      }
    }
  }
}

// ---------------- windowed attention (flash-style) ----------------
// grid: (qb=6, head=4, win=64). block 256 = 4 waves; wave owns 16 q-rows.
// keys: 0..359 in-window (t*45+p), 360..1319 rolled (t*120+vi via VR_TAB).
__global__ __launch_bounds__(256) void attn_kernel(const short* __restrict__ qkv,
                                                   short* __restrict__ aout) {
  const int qb = blockIdx.x, h = blockIdx.y, win = blockIdx.z;
  const int b = win >> 4, hb = (win >> 2) & 3, wb = win & 3;
  const int tid = threadIdx.x;
  const int wave = tid >> 6, lane = tid & 63, lg = lane >> 4, lc = lane & 15;

  __shared__ short Kc[64][136];   // keys row-major [key][d], padded stride
  __shared__ short Vt[128][72];   // V transposed [d][key], padded stride
  __shared__ short Pl[4][16][40]; // per-wave P bounce [q][key32], padded

  // Q A-fragments: row = lc, d = ks*32 + lg*8 + j
  int qa = qb*64 + wave*16 + lc; if (qa > 359) qa = 359;
  int tq = qa / 45, pq = qa - tq * 45;
  int mq = ((b*8 + tq)*20 + hb*5 + pq/9)*36 + wb*9 + (pq%9);
  const short* qptr = qkv + (size_t)mq * 1536 + h*128 + lg*8;
  short8 a_q[4];
  #pragma unroll
  for (int ks = 0; ks < 4; ++ks) a_q[ks] = *(const short8*)(qptr + ks*32);

  float m_run[4], l_run[4];
  f32x4 o_acc[8];
  #pragma unroll
  for (int i = 0; i < 4; ++i) { m_run[i] = -INFINITY; l_run[i] = 0.f; }
  #pragma unroll
  for (int dt = 0; dt < 8; ++dt) { o_acc[dt][0]=0.f; o_acc[dt][1]=0.f; o_acc[dt][2]=0.f; o_acc[dt][3]=0.f; }

  const int kl = tid >> 2, qpart = tid & 3;

  for (int c0 = 0; c0 < 21; ++c0) {
    // ---- stage 64 keys (K row-major, V transposed) ----
    int n = c0*64 + kl;
    bool valid = (n < 1320);
    int mk = 0;
    if (valid) {
      int t, gh, gw;
      if (n < 360) {
        t = n / 45; int p = n - t*45;
        gh = hb*5 + p/9; gw = wb*9 + (p%9);
      } else {
        int n2 = n - 360; t = n2 / 120; int vi = n2 - t*120;
        int f = VR_TAB[vi]; int s = f / 45; int p = f - s*45;
        int r = p / 9, cc = p - r*9;
        int sh0 = (s < 2) ? -2 : 2;
        int sh1 = (s & 1) ? 4 : -4;
        gh = (hb*5 + r - sh0 + 20) % 20;
        gw = (wb*9 + cc - sh1 + 36) % 36;
      }
      mk = ((b*8 + t)*20 + gh)*36 + gw;
    }
    const short* kp = qkv + (size_t)mk * 1536 + 512 + h*128 + qpart*32;
    #pragma unroll
    for (int u = 0; u < 4; ++u) {
      short8 kv = {0,0,0,0,0,0,0,0};
      short8 vv = {0,0,0,0,0,0,0,0};
      if (valid) {
        kv = *(const short8*)(kp + u*8);
        vv = *(const short8*)(kp + 512 + u*8);
      }
      int d0 = qpart*32 + u*8;
      *(short8*)&Kc[kl][d0] = kv;
      #pragma unroll
      for (int jj = 0; jj < 8; ++jj) Vt[d0 + jj][kl] = vv[jj];
    }
    __syncthreads();

    #pragma unroll
    for (int kt2 = 0; kt2 < 2; ++kt2) {
      const int kb = kt2 * 32;
      f32x4 s0, s1;
      s0[0]=0.f;s0[1]=0.f;s0[2]=0.f;s0[3]=0.f;
      s1[0]=0.f;s1[1]=0.f;s1[2]=0.f;s1[3]=0.f;
      #pragma unroll
      for (int ks = 0; ks < 4; ++ks) {
        short8 b0 = *(const short8*)&Kc[kb + lc][ks*32 + lg*8];
        short8 b1 = *(const short8*)&Kc[kb + 16 + lc][ks*32 + lg*8];
        s0 = MFMA16(a_q[ks], b0, s0);
        s1 = MFMA16(a_q[ks], b1, s1);
      }
      int key0 = c0*64 + kb + lc;
      bool v0k = key0 < 1320, v1k = (key0 + 16) < 1320;
      float p0[4], p1[4], fs[4];
      #pragma unroll
      for (int i = 0; i < 4; ++i) {
        float a0 = v0k ? s0[i] * SCALE_F : -1e30f;
        float a1 = v1k ? s1[i] * SCALE_F : -1e30f;
        float tm = fmaxf(a0, a1);
        for (int off = 1; off < 16; off <<= 1) tm = fmaxf(tm, __shfl_xor(tm, off));
        float mn = fmaxf(m_run[i], tm);
        float f = __expf(m_run[i] - mn);
        p0[i] = __expf(a0 - mn);
        p1[i] = __expf(a1 - mn);
        float ps = p0[i] + p1[i];
        for (int off = 1; off < 16; off <<= 1) ps += __shfl_xor(ps, off);
        l_run[i] = l_run[i] * f + ps;
        m_run[i] = mn;
        fs[i] = f;
      }
      #pragma unroll
      for (int dt = 0; dt < 8; ++dt)
        #pragma unroll
        for (int i = 0; i < 4; ++i) o_acc[dt][i] *= fs[i];
      // P bounce: D row 4*lg+i -> A-frag row lc
      #pragma unroll
      for (int i = 0; i < 4; ++i) {
        Pl[wave][4*lg + i][lc]      = f2bf(p0[i]);
        Pl[wave][4*lg + i][16 + lc] = f2bf(p1[i]);
      }
      __syncthreads();
      short8 pa = *(const short8*)&Pl[wave][lc][lg*8];
      #pragma unroll
      for (int dt = 0; dt < 8; ++dt) {
        short8 bv = *(const short8*)&Vt[dt*16 + lc][kb + lg*8];
        o_acc[dt] = MFMA16(pa, bv, o_acc[dt]);
      }
      __syncthreads();
    }
  }
  // epilogue: O row 4*lg+i, col dt*16+lc
  #pragma unroll
  for (int i = 0; i < 4; ++i) {
    int q = qb*64 + wave*16 + 4*lg + i;
    if (q >= 360) continue;
    float inv = 1.0f / l_run[i];
    int t = q / 45, p = q - t*45;
    int m = ((b*8 + t)*20 + hb*5 + p/9)*36 + wb*9 + (p%9);
    short* op = aout + (size_t)m * 512 + h*128 + lc;
    #pragma unroll
    for (int dt = 0; dt < 8; ++dt) op[dt*16] = f2bf(o_acc[dt][i] * inv);
  }
}

// ---------------- fold/unfold smoothing: h1(bf16 [23040][1960]) -> smooth f32 [32][40][60][108]
__global__ __launch_bounds__(256) void smooth_kernel(const short* __restrict__ h1,
                                                     float* __restrict__ sm) {
  int t = blockIdx.x * 256 + threadIdx.x;
  if (t >= 32*40*60*108) return;
  int x = t % 108;
  int y = (t / 108) % 60;
  int c40 = (t / 6480) % 40;
  int n = t / 259200;
  float s = 0.f; int cnt = 0;
  int kh0 = y % 3, kw0 = x % 3;
  for (int kh = kh0; kh < 7; kh += 3) {
    int dy = y + 3 - kh;
    if (dy < 0) continue;
    int oy = dy / 3;
    if (oy >= 20) continue;
    for (int kw = kw0; kw < 7; kw += 3) {
      int dx = x + 3 - kw;
      if (dx < 0) continue;
      int ox = dx / 3;
      if (ox >= 36) continue;
      s += bf2f(h1[(size_t)(n*720 + oy*36 + ox) * 1960 + c40*49 + kh*7 + kw]);
      ++cnt;
    }
  }
  sm[t] = s / (float)cnt;
}

// ---------------- conv+gelu v2: one block per (c40, n) plane, all taps from LDS ----------
// plane 60x108 f32 (26KB) + 49 filters (<=4.9KB) + 49 biases in LDS; 31KB total -> 5 blocks/CU.
// outputs idx = sp*49 + k  (k innermost -> near-contiguous bf16 stores).
__global__ __launch_bounds__(256) void conv_gelu_kernel(
    const float* __restrict__ sm,
    const float* __restrict__ w3, const float* __restrict__ b3,
    const float* __restrict__ w5, const float* __restrict__ b5,
    short* __restrict__ h3) {
  const int c40 = blockIdx.x, n = blockIdx.y;
  const int tid = threadIdx.x;
  __shared__ float plane[6480];
  __shared__ float wl[1225];
  __shared__ float wb[49];
  const float* smp = sm + (size_t)(n*40 + c40) * 6480;
  #pragma unroll
  for (int it = 0; it < 7; ++it) {
    int i4 = it*256 + tid;
    if (i4 < 1620) ((f32x4*)plane)[i4] = ((const f32x4*)smp)[i4];
  }
  const bool is3 = (c40 < 20);
  const int W = is3 ? 9 : 25;
  const int tot = 49 * W;
  const float* wsrc = is3 ? (w3 + c40*441) : (w5 + (size_t)(c40-20)*1225);
  for (int i = tid; i < tot; i += 256) wl[i] = wsrc[i];
  if (tid < 49) wb[tid] = is3 ? b3[c40*49 + tid] : b5[(c40-20)*49 + tid];
  __syncthreads();
  const size_t obase = (size_t)n*720*1960 + c40*49;
  for (int it = 0; it < 138; ++it) {
    int idx = it*256 + tid;
    if (idx >= 35280) break;
    int sp = idx / 49, k = idx - sp*49;
    int gh = sp / 36, gw = sp - gh*36;
    int kh = k / 7,  kw = k - kh*7;
    float acc = wb[k];
    if (is3) {
      #pragma unroll
      for (int dy = -1; dy <= 1; ++dy) {
        int iy = gh + dy; int y = kh + 3*iy - 3;
        if ((unsigned)iy >= 20u || (unsigned)y >= 60u) continue;
        #pragma unroll
        for (int dx = -1; dx <= 1; ++dx) {
          int ix = gw + dx; int x = kw + 3*ix - 3;
          if ((unsigned)ix >= 36u || (unsigned)x >= 108u) continue;
          acc += wl[k*9 + (dy+1)*3 + (dx+1)] * plane[y*108 + x];
        }
      }
    } else {
      #pragma unroll
      for (int dy = -2; dy <= 2; ++dy) {
        int iy = gh + dy; int y = kh + 3*iy - 3;
        if ((unsigned)iy >= 20u || (unsigned)y >= 60u) continue;
        #pragma unroll
        for (int dx = -2; dx <= 2; ++dx) {
          int ix = gw + dx; int x = kw + 3*ix - 3;
          if ((unsigned)ix >= 36u || (unsigned)x >= 108u) continue;
          acc += wl[k*25 + (dy+2)*5 + (dx+2)] * plane[y*108 + x];
        }
      }
    }
    float g = 0.5f * acc * (1.f + erff(acc * 0.70710678118654752f));
    h3[obase + (size_t)sp*1960 + k] = f2bf(g);
  }
}

// ---------------- launch ----------------
extern "C" void kernel_launch(void* const* d_in, const int* in_sizes, int n_in,
                              void* d_out, int out_size, void* d_ws, size_t ws_size,
                              hipStream_t stream) {
  const float* x      = (const float*)d_in[0];
  const float* ln1_g  = (const float*)d_in[1];
  const float* ln1_b  = (const float*)d_in[2];
  const float* ln2_g  = (const float*)d_in[3];
  const float* ln2_b  = (const float*)d_in[4];
  const float* w_qkv  = (const float*)d_in[5];
  const float* b_qkv  = (const float*)d_in[6];
  const float* w_proj = (const float*)d_in[7];
  const float* b_proj = (const float*)d_in[8];
  const float* w_fc1  = (const float*)d_in[9];
  const float* b_fc1  = (const float*)d_in[10];
  const float* w_c3   = (const float*)d_in[11];
  const float* b_c3   = (const float*)d_in[12];
  const float* w_c5   = (const float*)d_in[13];
  const float* b_c5   = (const float*)d_in[14];
  const float* w_fc2  = (const float*)d_in[15];
  const float* b_fc2  = (const float*)d_in[16];

  char* ws = (char*)d_ws;
  short* wqkvT  = (short*)(ws + 0);            // 1,572,864
  short* wprojT = (short*)(ws + 1572864);      //   524,288
  short* wfc1T  = (short*)(ws + 2097152);      // 2,007,040
  short* wfc2T  = (short*)(ws + 4104192);      // 2,007,040
  short* lnb    = (short*)(ws + 6111232);      // 23,592,960  (ln1 out, later ln2 out)
  short* bigb   = (short*)(ws + 29704192);     // 90,316,800  (qkv -> h1 -> h3)
  short* attnb  = (short*)(ws + 120020992);    // 23,592,960
  float* x2     = (float*)(ws + 143613952);    // 47,185,920
  float* smooth = (float*)(ws + 190799872);    // 33,177,600  (total 223,977,472)

  // bf16 transposed weights
  wtrans_kernel<<<(512*1536 + 255)/256, 256, 0, stream>>>(w_qkv, wqkvT, 512, 1536);
  wtrans_kernel<<<(512*512  + 255)/256, 256, 0, stream>>>(w_proj, wprojT, 512, 512);
  wtrans_kernel<<<(512*1960 + 255)/256, 256, 0, stream>>>(w_fc1, wfc1T, 512, 1960);
  wtrans_kernel<<<(1960*512 + 255)/256, 256, 0, stream>>>(w_fc2, wfc2T, 1960, 512);

  // attention branch
  ln_kernel<<<5760, 256, 0, stream>>>(x, ln1_g, ln1_b, lnb);
  gemm_kernel<1,0><<<dim3(180,12), 256, 0, stream>>>(lnb, wqkvT, b_qkv, nullptr, bigb, 1536, 512);
  attn_kernel<<<dim3(6,4,64), 256, 0, stream>>>(bigb, attnb);
  gemm_kernel<0,1><<<dim3(180,4), 256, 0, stream>>>(attnb, wprojT, b_proj, x, x2, 512, 512);

  // FFN branch
  ln_kernel<<<5760, 256, 0, stream>>>(x2, ln2_g, ln2_b, lnb);
  gemm_kernel<1,0><<<dim3(180,16), 256, 0, stream>>>(lnb, wfc1T, b_fc1, nullptr, bigb, 1960, 512);
  smooth_kernel<<<(32*40*60*108 + 255)/256, 256, 0, stream>>>(bigb, smooth);
  conv_gelu_kernel<<<dim3(40, 32), 256, 0, stream>>>(smooth, w_c3, b_c3, w_c5, b_c5, bigb);
  gemm_kernel<0,1><<<dim3(180,4), 256, 0, stream>>>(bigb, wfc2T, b_fc2, x2, (float*)d_out, 512, 1960);
}

// Round 5
// 1045.321 us; speedup vs baseline: 2.0280x; 1.1725x over previous
//
#include <hip/hip_runtime.h>
#include <hip/hip_bf16.h>
#include <math.h>

typedef __attribute__((ext_vector_type(8))) short short8;
typedef __attribute__((ext_vector_type(4))) float f32x4;

#define MFMA16(a,b,c) __builtin_amdgcn_mfma_f32_16x16x32_bf16((a),(b),(c),0,0,0)

__device__ __forceinline__ short f2bf(float f) {
  unsigned u = __builtin_bit_cast(unsigned, f);
  u += 0x7fffu + ((u >> 16) & 1u);
  return (short)(u >> 16);
}
__device__ __forceinline__ float bf2f(short s) {
  unsigned u = ((unsigned)(unsigned short)s) << 16;
  return __builtin_bit_cast(float, u);
}

#define SCALE_F 0.08838834764831845f

// valid rolled-window indices (VALID_ROLLED from reference, 120 entries)
__device__ const int VR_TAB[120] = {
  5,6,7,8,14,15,16,17,23,24,25,26,27,28,29,30,31,32,33,34,35,36,37,38,39,40,41,42,43,44,
  45,46,47,48,54,55,56,57,63,64,65,66,72,73,74,75,76,77,78,79,80,81,82,83,84,85,86,87,88,89,
  90,91,92,93,94,95,96,97,98,99,100,101,102,103,104,105,106,107,113,114,115,116,122,123,124,125,131,132,133,134,
  135,136,137,138,139,140,141,142,143,144,145,146,147,148,149,150,151,152,153,154,155,156,162,163,164,165,171,172,173,174
};

// ---------------- weight transpose f32[K][N] -> bf16[N][K] ----------------
__global__ __launch_bounds__(256) void wtrans_kernel(const float* __restrict__ w,
                                                     short* __restrict__ wt, int K, int N) {
  int idx = blockIdx.x * 256 + threadIdx.x;
  if (idx >= K * N) return;
  int k = idx / N, n = idx - k * N;
  wt[(size_t)n * K + k] = f2bf(w[idx]);
}

// ---------------- layernorm over C=512, f32 in -> bf16 out ----------------
__global__ __launch_bounds__(256) void ln_kernel(const float* __restrict__ x,
                                                 const float* __restrict__ g,
                                                 const float* __restrict__ be,
                                                 short* __restrict__ out) {
  typedef __attribute__((ext_vector_type(4))) float fx4;
  int row = blockIdx.x * 4 + (threadIdx.x >> 6);
  int lane = threadIdx.x & 63;
  const float* xr = x + (size_t)row * 512 + lane * 8;
  fx4 a = *(const fx4*)xr;
  fx4 c = *(const fx4*)(xr + 4);
  float s = a[0]+a[1]+a[2]+a[3]+c[0]+c[1]+c[2]+c[3];
  float ss = a[0]*a[0]+a[1]*a[1]+a[2]*a[2]+a[3]*a[3]+c[0]*c[0]+c[1]*c[1]+c[2]*c[2]+c[3]*c[3];
  for (int off = 1; off < 64; off <<= 1) {
    s  += __shfl_xor(s, off);
    ss += __shfl_xor(ss, off);
  }
  float mean = s * (1.0f/512.0f);
  float var  = ss * (1.0f/512.0f) - mean*mean;
  float rstd = rsqrtf(var + 1e-5f);
  const float* gp = g + lane*8;
  const float* bp = be + lane*8;
  short8 o;
  #pragma unroll
  for (int j = 0; j < 4; ++j) o[j]   = f2bf((a[j]-mean)*rstd*gp[j]   + bp[j]);
  #pragma unroll
  for (int j = 0; j < 4; ++j) o[4+j] = f2bf((c[j]-mean)*rstd*gp[4+j] + bp[4+j]);
  *(short8*)(out + (size_t)row * 512 + lane * 8) = o;
}

// ---------------- GEMM: C[M,N] = A[M,K](bf16) @ Bt[N,K]^T(bf16) + bias (+resid) --------
// 128x128 tile, BK=32, 4 waves (2x2 of 64x64), mfma 16x16x32 bf16.
// LAYOUT 0: out[M][N].  LAYOUT 1 (h1T): out[(rowg/720)*1411200 + col*720 + rowg%720].
template<int OUT_BF16, int RESID, int LAYOUT>
__global__ __launch_bounds__(256) void gemm_kernel(
    const short* __restrict__ A, const short* __restrict__ Bt,
    const float* __restrict__ bias, const float* __restrict__ resid,
    void* __restrict__ outp, int N, int K) {
  const int m0 = blockIdx.x * 128, n0 = blockIdx.y * 128;
  const int tid = threadIdx.x;
  const int wave = tid >> 6, lane = tid & 63, lg = lane >> 4, lc = lane & 15;
  const int wr = wave >> 1, wc = wave & 1;
  __shared__ short As[128][40];   // +8 pad: conflict-free ds_read_b128
  __shared__ short Bs[128][40];
  f32x4 acc[4][4];
  #pragma unroll
  for (int i = 0; i < 4; ++i)
    #pragma unroll
    for (int j = 0; j < 4; ++j) { acc[i][j][0]=0.f; acc[i][j][1]=0.f; acc[i][j][2]=0.f; acc[i][j][3]=0.f; }
  const int steps = (K + 31) >> 5;
  for (int kt = 0; kt < steps; ++kt) {
    const int k0 = kt << 5;
    __syncthreads();
    #pragma unroll
    for (int it = 0; it < 2; ++it) {
      int row = (tid >> 2) + (it << 6);
      int kk = k0 + (tid & 3) * 8;
      short8 av = {0,0,0,0,0,0,0,0};
      short8 bv = {0,0,0,0,0,0,0,0};
      if (kk + 8 <= K) {
        av = *(const short8*)(A + (size_t)(m0 + row) * K + kk);
        int nrow = n0 + row;
        if (nrow < N) bv = *(const short8*)(Bt + (size_t)nrow * K + kk);
      }
      *(short8*)&As[row][(tid & 3) * 8] = av;
      *(short8*)&Bs[row][(tid & 3) * 8] = bv;
    }
    __syncthreads();
    short8 af[4], bfv[4];
    #pragma unroll
    for (int i = 0; i < 4; ++i) af[i]  = *(const short8*)&As[wr*64 + i*16 + lc][lg*8];
    #pragma unroll
    for (int j = 0; j < 4; ++j) bfv[j] = *(const short8*)&Bs[wc*64 + j*16 + lc][lg*8];
    #pragma unroll
    for (int i = 0; i < 4; ++i)
      #pragma unroll
      for (int j = 0; j < 4; ++j)
        acc[i][j] = MFMA16(af[i], bfv[j], acc[i][j]);
  }
  // epilogue: D row = 4*lg + r, col = lc within each 16x16
  #pragma unroll
  for (int j = 0; j < 4; ++j) {
    int col = n0 + wc*64 + j*16 + lc;
    if (col >= N) continue;
    float bb = bias[col];
    #pragma unroll
    for (int i = 0; i < 4; ++i) {
      #pragma unroll
      for (int r = 0; r < 4; ++r) {
        int rowg = m0 + wr*64 + i*16 + lg*4 + r;
        float v = acc[i][j][r] + bb;
        if (RESID) v += resid[(size_t)rowg * N + col];
        if (LAYOUT == 1) {
          int nn = rowg / 720, sp = rowg - nn*720;
          ((short*)outp)[(size_t)nn*1411200 + (size_t)col*720 + sp] = f2bf(v);
        } else if (OUT_BF16) {
          ((short*)outp)[(size_t)rowg * N + col] = f2bf(v);
        } else {
          ((float*)outp)[(size_t)rowg * N + col] = v;
        }
      }
    }
  }
}

// ---------------- windowed attention (flash-style) ----------------
__global__ __launch_bounds__(256) void attn_kernel(const short* __restrict__ qkv,
                                                   short* __restrict__ aout) {
  const int qb = blockIdx.x, h = blockIdx.y, win = blockIdx.z;
  const int b = win >> 4, hb = (win >> 2) & 3, wb = win & 3;
  const int tid = threadIdx.x;
  const int wave = tid >> 6, lane = tid & 63, lg = lane >> 4, lc = lane & 15;

  __shared__ short Kc[64][136];   // keys row-major [key][d], padded stride
  __shared__ short Vt[128][72];   // V transposed [d][key], padded stride
  __shared__ short Pl[4][16][40]; // per-wave P bounce [q][key32], padded

  int qa = qb*64 + wave*16 + lc; if (qa > 359) qa = 359;
  int tq = qa / 45, pq = qa - tq * 45;
  int mq = ((b*8 + tq)*20 + hb*5 + pq/9)*36 + wb*9 + (pq%9);
  const short* qptr = qkv + (size_t)mq * 1536 + h*128 + lg*8;
  short8 a_q[4];
  #pragma unroll
  for (int ks = 0; ks < 4; ++ks) a_q[ks] = *(const short8*)(qptr + ks*32);

  float m_run[4], l_run[4];
  f32x4 o_acc[8];
  #pragma unroll
  for (int i = 0; i < 4; ++i) { m_run[i] = -INFINITY; l_run[i] = 0.f; }
  #pragma unroll
  for (int dt = 0; dt < 8; ++dt) { o_acc[dt][0]=0.f; o_acc[dt][1]=0.f; o_acc[dt][2]=0.f; o_acc[dt][3]=0.f; }

  const int kl = tid >> 2, qpart = tid & 3;

  for (int c0 = 0; c0 < 21; ++c0) {
    int n = c0*64 + kl;
    bool valid = (n < 1320);
    int mk = 0;
    if (valid) {
      int t, gh, gw;
      if (n < 360) {
        t = n / 45; int p = n - t*45;
        gh = hb*5 + p/9; gw = wb*9 + (p%9);
      } else {
        int n2 = n - 360; t = n2 / 120; int vi = n2 - t*120;
        int f = VR_TAB[vi]; int s = f / 45; int p = f - s*45;
        int r = p / 9, cc = p - r*9;
        int sh0 = (s < 2) ? -2 : 2;
        int sh1 = (s & 1) ? 4 : -4;
        gh = (hb*5 + r - sh0 + 20) % 20;
        gw = (wb*9 + cc - sh1 + 36) % 36;
      }
      mk = ((b*8 + t)*20 + gh)*36 + gw;
    }
    const short* kp = qkv + (size_t)mk * 1536 + 512 + h*128 + qpart*32;
    #pragma unroll
    for (int u = 0; u < 4; ++u) {
      short8 kv = {0,0,0,0,0,0,0,0};
      short8 vv = {0,0,0,0,0,0,0,0};
      if (valid) {
        kv = *(const short8*)(kp + u*8);
        vv = *(const short8*)(kp + 512 + u*8);
      }
      int d0 = qpart*32 + u*8;
      *(short8*)&Kc[kl][d0] = kv;
      #pragma unroll
      for (int jj = 0; jj < 8; ++jj) Vt[d0 + jj][kl] = vv[jj];
    }
    __syncthreads();

    #pragma unroll
    for (int kt2 = 0; kt2 < 2; ++kt2) {
      const int kb = kt2 * 32;
      f32x4 s0, s1;
      s0[0]=0.f;s0[1]=0.f;s0[2]=0.f;s0[3]=0.f;
      s1[0]=0.f;s1[1]=0.f;s1[2]=0.f;s1[3]=0.f;
      #pragma unroll
      for (int ks = 0; ks < 4; ++ks) {
        short8 b0 = *(const short8*)&Kc[kb + lc][ks*32 + lg*8];
        short8 b1 = *(const short8*)&Kc[kb + 16 + lc][ks*32 + lg*8];
        s0 = MFMA16(a_q[ks], b0, s0);
        s1 = MFMA16(a_q[ks], b1, s1);
      }
      int key0 = c0*64 + kb + lc;
      bool v0k = key0 < 1320, v1k = (key0 + 16) < 1320;
      float p0[4], p1[4], fs[4];
      #pragma unroll
      for (int i = 0; i < 4; ++i) {
        float a0 = v0k ? s0[i] * SCALE_F : -1e30f;
        float a1 = v1k ? s1[i] * SCALE_F : -1e30f;
        float tm = fmaxf(a0, a1);
        for (int off = 1; off < 16; off <<= 1) tm = fmaxf(tm, __shfl_xor(tm, off));
        float mn = fmaxf(m_run[i], tm);
        float f = __expf(m_run[i] - mn);
        p0[i] = __expf(a0 - mn);
        p1[i] = __expf(a1 - mn);
        float ps = p0[i] + p1[i];
        for (int off = 1; off < 16; off <<= 1) ps += __shfl_xor(ps, off);
        l_run[i] = l_run[i] * f + ps;
        m_run[i] = mn;
        fs[i] = f;
      }
      #pragma unroll
      for (int dt = 0; dt < 8; ++dt)
        #pragma unroll
        for (int i = 0; i < 4; ++i) o_acc[dt][i] *= fs[i];
      #pragma unroll
      for (int i = 0; i < 4; ++i) {
        Pl[wave][4*lg + i][lc]      = f2bf(p0[i]);
        Pl[wave][4*lg + i][16 + lc] = f2bf(p1[i]);
      }
      __syncthreads();
      short8 pa = *(const short8*)&Pl[wave][lc][lg*8];
      #pragma unroll
      for (int dt = 0; dt < 8; ++dt) {
        short8 bv = *(const short8*)&Vt[dt*16 + lc][kb + lg*8];
        o_acc[dt] = MFMA16(pa, bv, o_acc[dt]);
      }
      __syncthreads();
    }
  }
  #pragma unroll
  for (int i = 0; i < 4; ++i) {
    int q = qb*64 + wave*16 + 4*lg + i;
    if (q >= 360) continue;
    float inv = 1.0f / l_run[i];
    int t = q / 45, p = q - t*45;
    int m = ((b*8 + t)*20 + hb*5 + p/9)*36 + wb*9 + (p%9);
    short* op = aout + (size_t)m * 512 + h*128 + lc;
    #pragma unroll
    for (int dt = 0; dt < 8; ++dt) op[dt*16] = f2bf(o_acc[dt][i] * inv);
  }
}

// ---------------- smooth v2: h1T slab gather, block per (c40, n) ----------------
// h1T layout: [n][1960 cols][720 sp]; slab for (c40,n) = 49 k-rows x 720 sp (70.6KB, L1/L2-hot)
__global__ __launch_bounds__(256) void smooth_kernel(const short* __restrict__ h1t,
                                                     float* __restrict__ sm) {
  const int c40 = blockIdx.x, n = blockIdx.y;
  const int tid = threadIdx.x;
  const short* slab = h1t + (size_t)n*1411200 + (size_t)c40*49*720;
  float* outp = sm + (size_t)(n*40 + c40) * 6480;
  for (int p = tid; p < 6480; p += 256) {
    int y = p / 108, x = p - y*108;
    int y3 = y/3, ym = y - 3*y3;
    int x3 = x/3, xm = x - 3*x3;
    int jlo = (y3 == 19) ? 1 : 0, jhi = (y3 == 0) ? 1 : 2;
    int ilo = (x3 == 35) ? 1 : 0, ihi = (x3 == 0) ? 1 : 2;
    float s = 0.f;
    for (int j = jlo; j <= jhi; ++j) {
      int kh = ym + 3*j, oy = y3 + 1 - j;
      for (int i = ilo; i <= ihi; ++i) {
        int kw = xm + 3*i, ox = x3 + 1 - i;
        s += bf2f(slab[(kh*7 + kw)*720 + oy*36 + ox]);
      }
    }
    float cnt = (float)((jhi-jlo+1)*(ihi-ilo+1));
    outp[p] = s * (1.0f/cnt);
  }
}

// ---------------- conv+gelu v3: per-k stride-3 sublattice + register sliding window ----
// Block per (c40, n). Zero-padded plane P[64][114] (origin +3,+3): all tap validity
// is absorbed by clamped offsets into guaranteed-zero border rows/cols.
// Task tt -> (gh = tt/49, k = tt%49); thread slides a 5x5 (or 3x3) window over gw:
// 5 (3) LDS reads + 25 (9) FMA per output, no per-tap bounds compares.
__global__ __launch_bounds__(256) void conv_gelu_kernel(
    const float* __restrict__ sm,
    const float* __restrict__ w3, const float* __restrict__ b3,
    const float* __restrict__ w5, const float* __restrict__ b5,
    short* __restrict__ h3) {
  const int c40 = blockIdx.x, n = blockIdx.y;
  const int tid = threadIdx.x;
  __shared__ float P[64*114];
  __shared__ float wl[1225];
  __shared__ float wb[49];
  #pragma unroll
  for (int i = 0; i < 8; ++i) {
    int i4 = i*256 + tid;
    if (i4 < 1824) ((f32x4*)P)[i4] = f32x4{0.f,0.f,0.f,0.f};
  }
  const bool is3 = (c40 < 20);
  {
    const int W = is3 ? 9 : 25;
    const float* wsrc = is3 ? (w3 + c40*441) : (w5 + (size_t)(c40-20)*1225);
    for (int i = tid; i < 49*W; i += 256) wl[i] = wsrc[i];
    if (tid < 49) wb[tid] = is3 ? b3[c40*49 + tid] : b5[(c40-20)*49 + tid];
  }
  __syncthreads();
  const float* smp = sm + (size_t)(n*40 + c40) * 6480;
  for (int i = tid; i < 6480; i += 256) {
    int Y = i / 108, X = i - Y*108;
    P[(Y+3)*114 + X+3] = smp[i];
  }
  __syncthreads();

  for (int tt = tid; tt < 980; tt += 256) {
    int gh = tt / 49, k = tt - gh*49;
    int kh = k / 7, kw = k - kh*7;
    size_t obase = ((size_t)(n*720 + gh*36))*1960 + c40*49 + k;
    float bias = wb[k];
    if (is3) {
      float wr_[3][3];
      #pragma unroll
      for (int r = 0; r < 3; ++r)
        #pragma unroll
        for (int c = 0; c < 3; ++c) wr_[r][c] = wl[k*9 + r*3 + c];
      int rb[3];
      #pragma unroll
      for (int r = 0; r < 3; ++r) {
        int iy = gh + r - 1;
        int Y = 3*iy + kh - 3;
        rb[r] = ((unsigned)iy < 20u) ? (Y+3)*114 : 0;
      }
      float win[3][3];
      #pragma unroll
      for (int c = 0; c < 2; ++c) {
        int ix = c - 1;
        int X3 = 3*ix + kw;           // = X+3
        int xo = ((unsigned)ix < 36u) ? X3 : 0;
        #pragma unroll
        for (int r = 0; r < 3; ++r) win[r][c] = P[rb[r] + xo];
      }
      #pragma unroll
      for (int gw = 0; gw < 36; ++gw) {
        {
          int ix = gw + 1;
          int X3 = 3*ix + kw;
          int xo = ((unsigned)ix < 36u) ? X3 : 0;
          const int slot = (gw+2)%3;
          #pragma unroll
          for (int r = 0; r < 3; ++r) win[r][slot] = P[rb[r] + xo];
        }
        float acc = bias;
        #pragma unroll
        for (int r = 0; r < 3; ++r)
          #pragma unroll
          for (int c = 0; c < 3; ++c) acc += wr_[r][c] * win[r][(gw+c)%3];
        float g = 0.5f*acc*(1.f+erff(acc*0.70710678118654752f));
        h3[obase + (size_t)gw*1960] = f2bf(g);
      }
    } else {
      float wr_[5][5];
      #pragma unroll
      for (int r = 0; r < 5; ++r)
        #pragma unroll
        for (int c = 0; c < 5; ++c) wr_[r][c] = wl[k*25 + r*5 + c];
      int rb[5];
      #pragma unroll
      for (int r = 0; r < 5; ++r) {
        int iy = gh + r - 2;
        int Y = 3*iy + kh - 3;
        rb[r] = ((unsigned)iy < 20u) ? (Y+3)*114 : 0;
      }
      float win[5][5];
      #pragma unroll
      for (int c = 0; c < 4; ++c) {
        int ix = c - 2;
        int X3 = 3*ix + kw;
        int xo = ((unsigned)ix < 36u) ? X3 : 0;
        #pragma unroll
        for (int r = 0; r < 5; ++r) win[r][c] = P[rb[r] + xo];
      }
      #pragma unroll
      for (int gw = 0; gw < 36; ++gw) {
        {
          int ix = gw + 2;
          int X3 = 3*ix + kw;
          int xo = ((unsigned)ix < 36u) ? X3 : 0;
          const int slot = (gw+4)%5;
          #pragma unroll
          for (int r = 0; r < 5; ++r) win[r][slot] = P[rb[r] + xo];
        }
        float acc = bias;
        #pragma unroll
        for (int r = 0; r < 5; ++r)
          #pragma unroll
          for (int c = 0; c < 5; ++c) acc += wr_[r][c] * win[r][(gw+c)%5];
        float g = 0.5f*acc*(1.f+erff(acc*0.70710678118654752f));
        h3[obase + (size_t)gw*1960] = f2bf(g);
      }
    }
  }
}

// ---------------- launch ----------------
extern "C" void kernel_launch(void* const* d_in, const int* in_sizes, int n_in,
                              void* d_out, int out_size, void* d_ws, size_t ws_size,
                              hipStream_t stream) {
  const float* x      = (const float*)d_in[0];
  const float* ln1_g  = (const float*)d_in[1];
  const float* ln1_b  = (const float*)d_in[2];
  const float* ln2_g  = (const float*)d_in[3];
  const float* ln2_b  = (const float*)d_in[4];
  const float* w_qkv  = (const float*)d_in[5];
  const float* b_qkv  = (const float*)d_in[6];
  const float* w_proj = (const float*)d_in[7];
  const float* b_proj = (const float*)d_in[8];
  const float* w_fc1  = (const float*)d_in[9];
  const float* b_fc1  = (const float*)d_in[10];
  const float* w_c3   = (const float*)d_in[11];
  const float* b_c3   = (const float*)d_in[12];
  const float* w_c5   = (const float*)d_in[13];
  const float* b_c5   = (const float*)d_in[14];
  const float* w_fc2  = (const float*)d_in[15];
  const float* b_fc2  = (const float*)d_in[16];

  char* ws = (char*)d_ws;
  short* wqkvT  = (short*)(ws + 0);            // 1,572,864
  short* wprojT = (short*)(ws + 1572864);      //   524,288
  short* wfc1T  = (short*)(ws + 2097152);      // 2,007,040
  short* wfc2T  = (short*)(ws + 4104192);      // 2,007,040
  short* lnb    = (short*)(ws + 6111232);      // 23,592,960  (ln1 out, later ln2 out)
  short* bigb   = (short*)(ws + 29704192);     // 90,316,800  (qkv -> h1T -> h3)
  short* attnb  = (short*)(ws + 120020992);    // 23,592,960
  float* x2     = (float*)(ws + 143613952);    // 47,185,920
  float* smooth = (float*)(ws + 190799872);    // 33,177,600  (total 223,977,472)

  // bf16 transposed weights
  wtrans_kernel<<<(512*1536 + 255)/256, 256, 0, stream>>>(w_qkv, wqkvT, 512, 1536);
  wtrans_kernel<<<(512*512  + 255)/256, 256, 0, stream>>>(w_proj, wprojT, 512, 512);
  wtrans_kernel<<<(512*1960 + 255)/256, 256, 0, stream>>>(w_fc1, wfc1T, 512, 1960);
  wtrans_kernel<<<(1960*512 + 255)/256, 256, 0, stream>>>(w_fc2, wfc2T, 1960, 512);

  // attention branch
  ln_kernel<<<5760, 256, 0, stream>>>(x, ln1_g, ln1_b, lnb);
  gemm_kernel<1,0,0><<<dim3(180,12), 256, 0, stream>>>(lnb, wqkvT, b_qkv, nullptr, bigb, 1536, 512);
  attn_kernel<<<dim3(6,4,64), 256, 0, stream>>>(bigb, attnb);
  gemm_kernel<0,1,0><<<dim3(180,4), 256, 0, stream>>>(attnb, wprojT, b_proj, x, x2, 512, 512);

  // FFN branch
  ln_kernel<<<5760, 256, 0, stream>>>(x2, ln2_g, ln2_b, lnb);
  gemm_kernel<1,0,1><<<dim3(180,16), 256, 0, stream>>>(lnb, wfc1T, b_fc1, nullptr, bigb, 1960, 512);
  smooth_kernel<<<dim3(40,32), 256, 0, stream>>>(bigb, smooth);
  conv_gelu_kernel<<<dim3(40,32), 256, 0, stream>>>(smooth, w_c3, b_c3, w_c5, b_c5, bigb);
  gemm_kernel<0,1,0><<<dim3(180,4), 256, 0, stream>>>(bigb, wfc2T, b_fc2, x2, (float*)d_out, 512, 1960);
}

// Round 6
// 1030.217 us; speedup vs baseline: 2.0577x; 1.0147x over previous
//
#include <hip/hip_runtime.h>
#include <hip/hip_bf16.h>
#include <math.h>

typedef __attribute__((ext_vector_type(8))) short short8;
typedef __attribute__((ext_vector_type(4))) float f32x4;
typedef __attribute__((ext_vector_type(4))) int int4v;

#define MFMA16(a,b,c) __builtin_amdgcn_mfma_f32_16x16x32_bf16((a),(b),(c),0,0,0)

__device__ __forceinline__ short f2bf(float f) {
  unsigned u = __builtin_bit_cast(unsigned, f);
  u += 0x7fffu + ((u >> 16) & 1u);
  return (short)(u >> 16);
}
__device__ __forceinline__ float bf2f(short s) {
  unsigned u = ((unsigned)(unsigned short)s) << 16;
  return __builtin_bit_cast(float, u);
}
__device__ __forceinline__ unsigned packbf(float lo, float hi) {
  return (unsigned)(unsigned short)f2bf(lo) | ((unsigned)(unsigned short)f2bf(hi) << 16);
}

#define SCALE_F 0.08838834764831845f

// valid rolled-window indices (VALID_ROLLED from reference, 120 entries)
__device__ const int VR_TAB[120] = {
  5,6,7,8,14,15,16,17,23,24,25,26,27,28,29,30,31,32,33,34,35,36,37,38,39,40,41,42,43,44,
  45,46,47,48,54,55,56,57,63,64,65,66,72,73,74,75,76,77,78,79,80,81,82,83,84,85,86,87,88,89,
  90,91,92,93,94,95,96,97,98,99,100,101,102,103,104,105,106,107,113,114,115,116,122,123,124,125,131,132,133,134,
  135,136,137,138,139,140,141,142,143,144,145,146,147,148,149,150,151,152,153,154,155,156,162,163,164,165,171,172,173,174
};

// ---------------- weight transpose f32[K][N] -> bf16[N][K] ----------------
__global__ __launch_bounds__(256) void wtrans_kernel(const float* __restrict__ w,
                                                     short* __restrict__ wt, int K, int N) {
  int idx = blockIdx.x * 256 + threadIdx.x;
  if (idx >= K * N) return;
  int k = idx / N, n = idx - k * N;
  wt[(size_t)n * K + k] = f2bf(w[idx]);
}

// ---------------- layernorm over C=512, f32 in -> bf16 out ----------------
__global__ __launch_bounds__(256) void ln_kernel(const float* __restrict__ x,
                                                 const float* __restrict__ g,
                                                 const float* __restrict__ be,
                                                 short* __restrict__ out) {
  typedef __attribute__((ext_vector_type(4))) float fx4;
  int row = blockIdx.x * 4 + (threadIdx.x >> 6);
  int lane = threadIdx.x & 63;
  const float* xr = x + (size_t)row * 512 + lane * 8;
  fx4 a = *(const fx4*)xr;
  fx4 c = *(const fx4*)(xr + 4);
  float s = a[0]+a[1]+a[2]+a[3]+c[0]+c[1]+c[2]+c[3];
  float ss = a[0]*a[0]+a[1]*a[1]+a[2]*a[2]+a[3]*a[3]+c[0]*c[0]+c[1]*c[1]+c[2]*c[2]+c[3]*c[3];
  for (int off = 1; off < 64; off <<= 1) {
    s  += __shfl_xor(s, off);
    ss += __shfl_xor(ss, off);
  }
  float mean = s * (1.0f/512.0f);
  float var  = ss * (1.0f/512.0f) - mean*mean;
  float rstd = rsqrtf(var + 1e-5f);
  const float* gp = g + lane*8;
  const float* bp = be + lane*8;
  short8 o;
  #pragma unroll
  for (int j = 0; j < 4; ++j) o[j]   = f2bf((a[j]-mean)*rstd*gp[j]   + bp[j]);
  #pragma unroll
  for (int j = 0; j < 4; ++j) o[4+j] = f2bf((c[j]-mean)*rstd*gp[4+j] + bp[4+j]);
  *(short8*)(out + (size_t)row * 512 + lane * 8) = o;
}

// ---------------- GEMM: C[M,N] = A[M,K](bf16) @ Bt[N,K]^T(bf16) + bias (+resid) --------
template<int OUT_BF16, int RESID, int LAYOUT>
__global__ __launch_bounds__(256) void gemm_kernel(
    const short* __restrict__ A, const short* __restrict__ Bt,
    const float* __restrict__ bias, const float* __restrict__ resid,
    void* __restrict__ outp, int N, int K) {
  const int m0 = blockIdx.x * 128, n0 = blockIdx.y * 128;
  const int tid = threadIdx.x;
  const int wave = tid >> 6, lane = tid & 63, lg = lane >> 4, lc = lane & 15;
  const int wr = wave >> 1, wc = wave & 1;
  __shared__ short As[128][40];
  __shared__ short Bs[128][40];
  f32x4 acc[4][4];
  #pragma unroll
  for (int i = 0; i < 4; ++i)
    #pragma unroll
    for (int j = 0; j < 4; ++j) { acc[i][j][0]=0.f; acc[i][j][1]=0.f; acc[i][j][2]=0.f; acc[i][j][3]=0.f; }
  const int steps = (K + 31) >> 5;
  for (int kt = 0; kt < steps; ++kt) {
    const int k0 = kt << 5;
    __syncthreads();
    #pragma unroll
    for (int it = 0; it < 2; ++it) {
      int row = (tid >> 2) + (it << 6);
      int kk = k0 + (tid & 3) * 8;
      short8 av = {0,0,0,0,0,0,0,0};
      short8 bv = {0,0,0,0,0,0,0,0};
      if (kk + 8 <= K) {
        av = *(const short8*)(A + (size_t)(m0 + row) * K + kk);
        int nrow = n0 + row;
        if (nrow < N) bv = *(const short8*)(Bt + (size_t)nrow * K + kk);
      }
      *(short8*)&As[row][(tid & 3) * 8] = av;
      *(short8*)&Bs[row][(tid & 3) * 8] = bv;
    }
    __syncthreads();
    short8 af[4], bfv[4];
    #pragma unroll
    for (int i = 0; i < 4; ++i) af[i]  = *(const short8*)&As[wr*64 + i*16 + lc][lg*8];
    #pragma unroll
    for (int j = 0; j < 4; ++j) bfv[j] = *(const short8*)&Bs[wc*64 + j*16 + lc][lg*8];
    #pragma unroll
    for (int i = 0; i < 4; ++i)
      #pragma unroll
      for (int j = 0; j < 4; ++j)
        acc[i][j] = MFMA16(af[i], bfv[j], acc[i][j]);
  }
  #pragma unroll
  for (int j = 0; j < 4; ++j) {
    int col = n0 + wc*64 + j*16 + lc;
    if (col >= N) continue;
    float bb = bias[col];
    #pragma unroll
    for (int i = 0; i < 4; ++i) {
      #pragma unroll
      for (int r = 0; r < 4; ++r) {
        int rowg = m0 + wr*64 + i*16 + lg*4 + r;
        float v = acc[i][j][r] + bb;
        if (RESID) v += resid[(size_t)rowg * N + col];
        if (LAYOUT == 1) {
          int nn = rowg / 720, sp = rowg - nn*720;
          ((short*)outp)[(size_t)nn*1411200 + (size_t)col*720 + sp] = f2bf(v);
        } else if (OUT_BF16) {
          ((short*)outp)[(size_t)rowg * N + col] = f2bf(v);
        } else {
          ((float*)outp)[(size_t)rowg * N + col] = v;
        }
      }
    }
  }
}

// ---------------- windowed attention v2: swapped QK^T, in-register softmax ----------
// grid: (qb=6, head=4, win=64). block 256 = 4 waves; wave owns 16 q-rows (q = lc).
// S^T = mfma(K,Q): lane holds 16 key-scores for query q=lc -> in-lane softmax,
// 4 shfl_xor for cross-lg reduce. P redistributed to PV A-frags via 16 uniform
// shfls. V^T in LDS with XOR-swizzled column blocks (conflict-free writes/reads).
__global__ __launch_bounds__(256) void attn_kernel(const short* __restrict__ qkv,
                                                   short* __restrict__ aout) {
  const int qb = blockIdx.x, h = blockIdx.y, win = blockIdx.z;
  const int b = win >> 4, hb = (win >> 2) & 3, wb = win & 3;
  const int tid = threadIdx.x;
  const int wave = tid >> 6, lane = tid & 63, lg = lane >> 4, lc = lane & 15;

  __shared__ short Kc[64][136];   // keys row-major [key][d]
  __shared__ short Vt[128][72];   // V^T [d][key], col-block XOR-swizzled

  // Q fragment (B operand): row = lc -> q, elements ks*32+lg*8..+7
  int qa = qb*64 + wave*16 + lc; if (qa > 359) qa = 359;
  int tq = qa / 45, pq = qa - tq * 45;
  int mq = ((b*8 + tq)*20 + hb*5 + pq/9)*36 + wb*9 + (pq%9);
  const short* qptr = qkv + (size_t)mq * 1536 + h*128 + lg*8;
  short8 q_f[4];
  #pragma unroll
  for (int ks = 0; ks < 4; ++ks) q_f[ks] = *(const short8*)(qptr + ks*32);

  float m_run = -INFINITY, l_run = 0.f;   // state for query q = lc
  f32x4 o_acc[8];                          // O[q=4lg+r][d=dt*16+lc]
  #pragma unroll
  for (int dt = 0; dt < 8; ++dt) { o_acc[dt][0]=0.f; o_acc[dt][1]=0.f; o_acc[dt][2]=0.f; o_acc[dt][3]=0.f; }

  const int kl = tid >> 2, qpart = tid & 3;

  for (int c0 = 0; c0 < 21; ++c0) {
    // ---- stage 64 keys ----
    int n = c0*64 + kl;
    bool valid = (n < 1320);
    int mk = 0;
    if (valid) {
      int t, gh, gw;
      if (n < 360) {
        t = n / 45; int p = n - t*45;
        gh = hb*5 + p/9; gw = wb*9 + (p%9);
      } else {
        int n2 = n - 360; t = n2 / 120; int vi = n2 - t*120;
        int f = VR_TAB[vi]; int s = f / 45; int p = f - s*45;
        int r = p / 9, cc = p - r*9;
        int sh0 = (s < 2) ? -2 : 2;
        int sh1 = (s & 1) ? 4 : -4;
        gh = (hb*5 + r - sh0 + 20) % 20;
        gw = (wb*9 + cc - sh1 + 36) % 36;
      }
      mk = ((b*8 + t)*20 + gh)*36 + gw;
    }
    const short* kp = qkv + (size_t)mk * 1536 + 512 + h*128 + qpart*32;
    #pragma unroll
    for (int u = 0; u < 4; ++u) {
      short8 kv = {0,0,0,0,0,0,0,0};
      short8 vv = {0,0,0,0,0,0,0,0};
      if (valid) {
        kv = *(const short8*)(kp + u*8);
        vv = *(const short8*)(kp + 512 + u*8);
      }
      int d0 = qpart*32 + u*8;
      *(short8*)&Kc[kl][d0] = kv;
      // Vt: col block a' = (kl>>3) ^ ((d>>5)<<1 | (d>>3)&1); here d>>5=qpart, (d>>3)&1=u&1
      int colb = (((kl>>3) ^ ((qpart<<1) | (u & 1))) << 3) | (kl & 7);
      #pragma unroll
      for (int jj = 0; jj < 8; ++jj) Vt[d0 + jj][colb] = vv[jj];
    }
    __syncthreads();

    // ---- QK^T swapped: S^T[key=t*16+4lg+r][q=lc] ----
    f32x4 sv[4];
    #pragma unroll
    for (int t = 0; t < 4; ++t) { sv[t][0]=0.f; sv[t][1]=0.f; sv[t][2]=0.f; sv[t][3]=0.f; }
    #pragma unroll
    for (int t = 0; t < 4; ++t)
      #pragma unroll
      for (int ks = 0; ks < 4; ++ks) {
        short8 kf = *(const short8*)&Kc[t*16 + lc][ks*32 + lg*8];
        sv[t] = MFMA16(kf, q_f[ks], sv[t]);
      }

    // ---- scale + mask ----
    if (c0 == 20) {
      #pragma unroll
      for (int t = 0; t < 4; ++t)
        #pragma unroll
        for (int r = 0; r < 4; ++r)
          sv[t][r] = (t*16 + 4*lg + r < 40) ? sv[t][r]*SCALE_F : -1e30f;
    } else {
      #pragma unroll
      for (int t = 0; t < 4; ++t)
        #pragma unroll
        for (int r = 0; r < 4; ++r) sv[t][r] *= SCALE_F;
    }

    // ---- online softmax (per-lane over 16 keys, cross-lg via 2 shfl) ----
    float mc = -INFINITY;
    #pragma unroll
    for (int t = 0; t < 4; ++t)
      #pragma unroll
      for (int r = 0; r < 4; ++r) mc = fmaxf(mc, sv[t][r]);
    mc = fmaxf(mc, __shfl_xor(mc, 16));
    mc = fmaxf(mc, __shfl_xor(mc, 32));
    float mn = fmaxf(m_run, mc);
    float f = __expf(m_run - mn);
    m_run = mn;
    float ps = 0.f;
    #pragma unroll
    for (int t = 0; t < 4; ++t)
      #pragma unroll
      for (int r = 0; r < 4; ++r) { sv[t][r] = __expf(sv[t][r] - mn); ps += sv[t][r]; }
    ps += __shfl_xor(ps, 16);
    ps += __shfl_xor(ps, 32);
    l_run = l_run * f + ps;

    // ---- pack P to bf16 pairs ----
    unsigned I[4][2];
    #pragma unroll
    for (int t = 0; t < 4; ++t) {
      I[t][0] = packbf(sv[t][0], sv[t][1]);
      I[t][1] = packbf(sv[t][2], sv[t][3]);
    }
    // ---- redistribute to PV A-frags: pa0 = keys lg*8..+7, pa1 = 32+lg*8..+7 ----
    int4v pa0, pa1;
    #pragma unroll
    for (int t = 0; t < 4; ++t)
      #pragma unroll
      for (int w = 0; w < 2; ++w)
        #pragma unroll
        for (int X = 0; X < 2; ++X) {
          int tmp = __shfl((int)I[t][w], ((lg & 1)*2 + X)*16 + lc);
          int m = 2*X + w;
          if ((lg >> 1) == (t & 1)) {
            if (t < 2) pa0[m] = tmp; else pa1[m] = tmp;
          }
        }
    short8 pa0s = __builtin_bit_cast(short8, pa0);
    short8 pa1s = __builtin_bit_cast(short8, pa1);

    // ---- rescale O, then PV ----
    float fr[4];
    #pragma unroll
    for (int r = 0; r < 4; ++r) fr[r] = __shfl(f, 4*lg + r);
    #pragma unroll
    for (int dt = 0; dt < 8; ++dt)
      #pragma unroll
      for (int r = 0; r < 4; ++r) o_acc[dt][r] *= fr[r];
    #pragma unroll
    for (int dt = 0; dt < 8; ++dt) {
      int d = dt*16 + lc;
      int swz = ((d >> 5) << 1) | ((d >> 3) & 1);
      short8 bv0 = *(const short8*)&Vt[d][((0 + lg) ^ swz) << 3];
      o_acc[dt] = MFMA16(pa0s, bv0, o_acc[dt]);
      short8 bv1 = *(const short8*)&Vt[d][((4 + lg) ^ swz) << 3];
      o_acc[dt] = MFMA16(pa1s, bv1, o_acc[dt]);
    }
    __syncthreads();
  }

  // ---- epilogue: O row q = 4lg+i, col d = dt*16+lc ----
  #pragma unroll
  for (int i = 0; i < 4; ++i) {
    int q = qb*64 + wave*16 + 4*lg + i;
    if (q >= 360) continue;
    float linv = 1.0f / __shfl(l_run, 4*lg + i);
    int t = q / 45, p = q - t*45;
    int m = ((b*8 + t)*20 + hb*5 + p/9)*36 + wb*9 + (p%9);
    short* op = aout + (size_t)m * 512 + h*128 + lc;
    #pragma unroll
    for (int dt = 0; dt < 8; ++dt) op[dt*16] = f2bf(o_acc[dt][i] * linv);
  }
}

// ---------------- smooth v2: h1T slab gather, block per (c40, n) ----------------
__global__ __launch_bounds__(256) void smooth_kernel(const short* __restrict__ h1t,
                                                     float* __restrict__ sm) {
  const int c40 = blockIdx.x, n = blockIdx.y;
  const int tid = threadIdx.x;
  const short* slab = h1t + (size_t)n*1411200 + (size_t)c40*49*720;
  float* outp = sm + (size_t)(n*40 + c40) * 6480;
  for (int p = tid; p < 6480; p += 256) {
    int y = p / 108, x = p - y*108;
    int y3 = y/3, ym = y - 3*y3;
    int x3 = x/3, xm = x - 3*x3;
    int jlo = (y3 == 19) ? 1 : 0, jhi = (y3 == 0) ? 1 : 2;
    int ilo = (x3 == 35) ? 1 : 0, ihi = (x3 == 0) ? 1 : 2;
    float s = 0.f;
    for (int j = jlo; j <= jhi; ++j) {
      int kh = ym + 3*j, oy = y3 + 1 - j;
      for (int i = ilo; i <= ihi; ++i) {
        int kw = xm + 3*i, ox = x3 + 1 - i;
        s += bf2f(slab[(kh*7 + kw)*720 + oy*36 + ox]);
      }
    }
    float cnt = (float)((jhi-jlo+1)*(ihi-ilo+1));
    outp[p] = s * (1.0f/cnt);
  }
}

// ---------------- conv+gelu v3: per-k stride-3 sublattice + register sliding window ----
__global__ __launch_bounds__(256) void conv_gelu_kernel(
    const float* __restrict__ sm,
    const float* __restrict__ w3, const float* __restrict__ b3,
    const float* __restrict__ w5, const float* __restrict__ b5,
    short* __restrict__ h3) {
  const int c40 = blockIdx.x, n = blockIdx.y;
  const int tid = threadIdx.x;
  __shared__ float P[64*114];
  __shared__ float wl[1225];
  __shared__ float wb[49];
  #pragma unroll
  for (int i = 0; i < 8; ++i) {
    int i4 = i*256 + tid;
    if (i4 < 1824) ((f32x4*)P)[i4] = f32x4{0.f,0.f,0.f,0.f};
  }
  const bool is3 = (c40 < 20);
  {
    const int W = is3 ? 9 : 25;
    const float* wsrc = is3 ? (w3 + c40*441) : (w5 + (size_t)(c40-20)*1225);
    for (int i = tid; i < 49*W; i += 256) wl[i] = wsrc[i];
    if (tid < 49) wb[tid] = is3 ? b3[c40*49 + tid] : b5[(c40-20)*49 + tid];
  }
  __syncthreads();
  const float* smp = sm + (size_t)(n*40 + c40) * 6480;
  for (int i = tid; i < 6480; i += 256) {
    int Y = i / 108, X = i - Y*108;
    P[(Y+3)*114 + X+3] = smp[i];
  }
  __syncthreads();

  for (int tt = tid; tt < 980; tt += 256) {
    int gh = tt / 49, k = tt - gh*49;
    int kh = k / 7, kw = k - kh*7;
    size_t obase = ((size_t)(n*720 + gh*36))*1960 + c40*49 + k;
    float bias = wb[k];
    if (is3) {
      float wr_[3][3];
      #pragma unroll
      for (int r = 0; r < 3; ++r)
        #pragma unroll
        for (int c = 0; c < 3; ++c) wr_[r][c] = wl[k*9 + r*3 + c];
      int rb[3];
      #pragma unroll
      for (int r = 0; r < 3; ++r) {
        int iy = gh + r - 1;
        int Y = 3*iy + kh - 3;
        rb[r] = ((unsigned)iy < 20u) ? (Y+3)*114 : 0;
      }
      float win[3][3];
      #pragma unroll
      for (int c = 0; c < 2; ++c) {
        int ix = c - 1;
        int X3 = 3*ix + kw;
        int xo = ((unsigned)ix < 36u) ? X3 : 0;
        #pragma unroll
        for (int r = 0; r < 3; ++r) win[r][c] = P[rb[r] + xo];
      }
      #pragma unroll
      for (int gw = 0; gw < 36; ++gw) {
        {
          int ix = gw + 1;
          int X3 = 3*ix + kw;
          int xo = ((unsigned)ix < 36u) ? X3 : 0;
          const int slot = (gw+2)%3;
          #pragma unroll
          for (int r = 0; r < 3; ++r) win[r][slot] = P[rb[r] + xo];
        }
        float acc = bias;
        #pragma unroll
        for (int r = 0; r < 3; ++r)
          #pragma unroll
          for (int c = 0; c < 3; ++c) acc += wr_[r][c] * win[r][(gw+c)%3];
        float g = 0.5f*acc*(1.f+erff(acc*0.70710678118654752f));
        h3[obase + (size_t)gw*1960] = f2bf(g);
      }
    } else {
      float wr_[5][5];
      #pragma unroll
      for (int r = 0; r < 5; ++r)
        #pragma unroll
        for (int c = 0; c < 5; ++c) wr_[r][c] = wl[k*25 + r*5 + c];
      int rb[5];
      #pragma unroll
      for (int r = 0; r < 5; ++r) {
        int iy = gh + r - 2;
        int Y = 3*iy + kh - 3;
        rb[r] = ((unsigned)iy < 20u) ? (Y+3)*114 : 0;
      }
      float win[5][5];
      #pragma unroll
      for (int c = 0; c < 4; ++c) {
        int ix = c - 2;
        int X3 = 3*ix + kw;
        int xo = ((unsigned)ix < 36u) ? X3 : 0;
        #pragma unroll
        for (int r = 0; r < 5; ++r) win[r][c] = P[rb[r] + xo];
      }
      #pragma unroll
      for (int gw = 0; gw < 36; ++gw) {
        {
          int ix = gw + 2;
          int X3 = 3*ix + kw;
          int xo = ((unsigned)ix < 36u) ? X3 : 0;
          const int slot = (gw+4)%5;
          #pragma unroll
          for (int r = 0; r < 5; ++r) win[r][slot] = P[rb[r] + xo];
        }
        float acc = bias;
        #pragma unroll
        for (int r = 0; r < 5; ++r)
          #pragma unroll
          for (int c = 0; c < 5; ++c) acc += wr_[r][c] * win[r][(gw+c)%5];
        float g = 0.5f*acc*(1.f+erff(acc*0.70710678118654752f));
        h3[obase + (size_t)gw*1960] = f2bf(g);
      }
    }
  }
}

// ---------------- launch ----------------
extern "C" void kernel_launch(void* const* d_in, const int* in_sizes, int n_in,
                              void* d_out, int out_size, void* d_ws, size_t ws_size,
                              hipStream_t stream) {
  const float* x      = (const float*)d_in[0];
  const float* ln1_g  = (const float*)d_in[1];
  const float* ln1_b  = (const float*)d_in[2];
  const float* ln2_g  = (const float*)d_in[3];
  const float* ln2_b  = (const float*)d_in[4];
  const float* w_qkv  = (const float*)d_in[5];
  const float* b_qkv  = (const float*)d_in[6];
  const float* w_proj = (const float*)d_in[7];
  const float* b_proj = (const float*)d_in[8];
  const float* w_fc1  = (const float*)d_in[9];
  const float* b_fc1  = (const float*)d_in[10];
  const float* w_c3   = (const float*)d_in[11];
  const float* b_c3   = (const float*)d_in[12];
  const float* w_c5   = (const float*)d_in[13];
  const float* b_c5   = (const float*)d_in[14];
  const float* w_fc2  = (const float*)d_in[15];
  const float* b_fc2  = (const float*)d_in[16];

  char* ws = (char*)d_ws;
  short* wqkvT  = (short*)(ws + 0);
  short* wprojT = (short*)(ws + 1572864);
  short* wfc1T  = (short*)(ws + 2097152);
  short* wfc2T  = (short*)(ws + 4104192);
  short* lnb    = (short*)(ws + 6111232);
  short* bigb   = (short*)(ws + 29704192);
  short* attnb  = (short*)(ws + 120020992);
  float* x2     = (float*)(ws + 143613952);
  float* smooth = (float*)(ws + 190799872);

  wtrans_kernel<<<(512*1536 + 255)/256, 256, 0, stream>>>(w_qkv, wqkvT, 512, 1536);
  wtrans_kernel<<<(512*512  + 255)/256, 256, 0, stream>>>(w_proj, wprojT, 512, 512);
  wtrans_kernel<<<(512*1960 + 255)/256, 256, 0, stream>>>(w_fc1, wfc1T, 512, 1960);
  wtrans_kernel<<<(1960*512 + 255)/256, 256, 0, stream>>>(w_fc2, wfc2T, 1960, 512);

  ln_kernel<<<5760, 256, 0, stream>>>(x, ln1_g, ln1_b, lnb);
  gemm_kernel<1,0,0><<<dim3(180,12), 256, 0, stream>>>(lnb, wqkvT, b_qkv, nullptr, bigb, 1536, 512);
  attn_kernel<<<dim3(6,4,64), 256, 0, stream>>>(bigb, attnb);
  gemm_kernel<0,1,0><<<dim3(180,4), 256, 0, stream>>>(attnb, wprojT, b_proj, x, x2, 512, 512);

  ln_kernel<<<5760, 256, 0, stream>>>(x2, ln2_g, ln2_b, lnb);
  gemm_kernel<1,0,1><<<dim3(180,16), 256, 0, stream>>>(lnb, wfc1T, b_fc1, nullptr, bigb, 1960, 512);
  smooth_kernel<<<dim3(40,32), 256, 0, stream>>>(bigb, smooth);
  conv_gelu_kernel<<<dim3(40,32), 256, 0, stream>>>(smooth, w_c3, b_c3, w_c5, b_c5, bigb);
  gemm_kernel<0,1,0><<<dim3(180,4), 256, 0, stream>>>(bigb, wfc2T, b_fc2, x2, (float*)d_out, 512, 1960);
}